// Round 4
// baseline (71.720 us; speedup 1.0000x reference)
//
#include <hip/hip_runtime.h>
#include <hip/hip_bf16.h>

// CorrelationLayerCosineSimilarity via banded bf16 MFMA GEMM.
// Per (b,h): Out[w,d] = sum_c x1[c,w]*x2p[c,w+d] / max(n1[w]*n2[w+d], 1e-6)
// B=4,C=256,H=128,W=256,D=41.
//
// Round 4: full occupancy. 512 blocks x 1024 thr (16 waves). Wave v stages
// channels {2v, 2v+1} per K-step and owns w-tile wt=v x 4 col-tiles.
// __launch_bounds__(1024,8) caps VGPR at 64 -> 2 blocks/CU = 32 waves/CU
// (round 3 was 16 waves/CU at 37% occupancy, latency-bound everywhere).
//
// LDS: A[w 0..255][kc 0..31] bf16 rows of 80B (4x16B slots + pad slot;
// logical slot s of row w at physical slot (s+w)%5 -> conflict-free b128
// frag reads). B[w' 0..303] same (rows 256..303 zeroed once). Norms live
// at NBASE (past the 16x4224B epilogue scratch). Epilogue: per-wave 16x66
// f32 transpose -> normalize -> coalesced [d][w] float4 stores.

#define B_   4
#define C_   256
#define H_   128
#define W_   256
#define ND_  41
#define HW_  (H_ * W_)
#define CHW_ (C_ * HW_)
#define EPS_ 1e-6f

typedef __attribute__((ext_vector_type(4))) float f32x4;
typedef __attribute__((ext_vector_type(8))) short bf16x8;

#define ABASE 0
#define BBASE 20480            // A: 256*80
#define NBASE 67584            // past epilogue scratch 16*4224
#define LDSZ  69824            // NBASE + 560*4

__device__ __forceinline__ unsigned bfr(float x) {   // fp32 -> bf16 bits, RNE
  unsigned u = __builtin_bit_cast(unsigned, x);
  return (u + 0x7fffu + ((u >> 16) & 1u)) >> 16;
}

__global__ __launch_bounds__(1024, 8)
void corr_mfma(const float* __restrict__ x1, const float* __restrict__ x2,
               float* __restrict__ out) {
  __shared__ __align__(16) char lds[LDSZ];

  const int tid = threadIdx.x;
  const int l   = tid & 63;
  const int v   = tid >> 6;          // wave id, 0..15
  const int m   = l & 15;
  const int g   = l >> 4;

  const int r = blockIdx.x;
  const int b = r >> 7;
  const int h = r & (H_ - 1);

  const float* X1 = x1 + b * CHW_ + h * W_;
  const float* X2 = x2 + b * CHW_ + h * W_;

  // ---- prologue zero-init: norm accumulators + B pad rows 256..303 ----
  if (tid < 560) ((float*)(lds + NBASE))[tid] = 0.f;
  if (tid < 960) ((unsigned*)(lds + BBASE + 256 * 80))[tid] = 0u;

  // ---- loop-invariant addresses ----
  int wadr[4];                        // staging write addrs (x1; x2 = +BBASE)
#pragma unroll
  for (int j = 0; j < 4; ++j) {
    int w = 4 * l + j;
    wadr[j] = ABASE + w * 80 + (((v >> 2) + w) % 5) * 16 + (v & 3) * 4;
  }
  const int rowA = 16 * v + m;
  const int adrA = ABASE + rowA * 80 + ((g + rowA) % 5) * 16;
  int adrB[4];
#pragma unroll
  for (int c = 0; c < 4; ++c) {
    int col = 16 * (v + c) + m;       // <= 16*18+15 = 303
    adrB[c] = BBASE + col * 80 + ((g + col) % 5) * 16;
  }

  f32x4 acc[4];
#pragma unroll
  for (int c = 0; c < 4; ++c) acc[c] = (f32x4){0.f, 0.f, 0.f, 0.f};
  float ssq1[4] = {0.f, 0.f, 0.f, 0.f}, ssq2[4] = {0.f, 0.f, 0.f, 0.f};

  // ---- prefetch K-step 0: wave v loads channels 2v, 2v+1 ----
  f32x4 r1[2], r2[2];
#pragma unroll
  for (int i = 0; i < 2; ++i) {
    r1[i] = *(const f32x4*)(X1 + (2 * v + i) * HW_ + 4 * l);
    r2[i] = *(const f32x4*)(X2 + (2 * v + i) * HW_ + 4 * l);
  }

  for (int ks = 0; ks < 8; ++ks) {
    __syncthreads();                  // prior compute done (iter0: zeros done)
    // ---- ssq + bf16 pack + transposed LDS write (k pair 2v,2v+1) ----
#pragma unroll
    for (int j = 0; j < 4; ++j) {
      ssq1[j] += r1[0][j] * r1[0][j] + r1[1][j] * r1[1][j];
      ssq2[j] += r2[0][j] * r2[0][j] + r2[1][j] * r2[1][j];
      unsigned p1 = bfr(r1[0][j]) | (bfr(r1[1][j]) << 16);
      unsigned p2 = bfr(r2[0][j]) | (bfr(r2[1][j]) << 16);
      *(unsigned*)(lds + wadr[j]) = p1;
      *(unsigned*)(lds + wadr[j] + BBASE) = p2;
    }
    __syncthreads();                  // tile ready
    if (ks < 7) {                     // prefetch next K-step (hides HBM)
      const float* p1 = X1 + ((ks + 1) * 32 + 2 * v) * HW_ + 4 * l;
      const float* p2 = X2 + ((ks + 1) * 32 + 2 * v) * HW_ + 4 * l;
#pragma unroll
      for (int i = 0; i < 2; ++i) {
        r1[i] = *(const f32x4*)(p1 + i * HW_);
        r2[i] = *(const f32x4*)(p2 + i * HW_);
      }
    }
    // ---- compute: 5 ds_read_b128 + 4 MFMA ----
    bf16x8 a0 = *(const bf16x8*)(lds + adrA);
#pragma unroll
    for (int c = 0; c < 4; ++c) {
      bf16x8 b0 = *(const bf16x8*)(lds + adrB[c]);
      acc[c] = __builtin_amdgcn_mfma_f32_16x16x32_bf16(a0, b0, acc[c], 0, 0, 0);
    }
  }

  // ---- norms: LDS atomic reduce of fp32 ssq, then sqrt in place ----
  float* nsq = (float*)(lds + NBASE);
#pragma unroll
  for (int j = 0; j < 4; ++j) {
    atomicAdd(nsq + 4 * l + j, ssq1[j]);            // n1sq[w]
    atomicAdd(nsq + 256 + 4 * l + j, ssq2[j]);      // n2sq[w'], w' < 256
  }
  __syncthreads();                    // also: all frag reads of A/B done
  if (tid < 560) nsq[tid] = sqrtf(nsq[tid]);        // n2sq[256..303] stay 0
  __syncthreads();

  // ---- epilogue: per-wave transpose -> normalize -> coalesced stores ----
  float* Sw  = (float*)(lds + v * 4224);            // 16 x 66 f32, own region
  float* n1s = nsq;                                 // [256]
  float* n2s = nsq + 256;                           // [304]
#pragma unroll
  for (int c = 0; c < 4; ++c)
#pragma unroll
    for (int rr = 0; rr < 4; ++rr)
      Sw[(4 * g + rr) * 66 + 16 * c + m] = acc[c][rr];   // D[row][col]
  // wave-internal LDS RAW: compiler inserts lgkmcnt wait
  const int wq = l & 3, dd = l >> 2;
  const int w0 = 16 * v + 4 * wq;
#pragma unroll
  for (int p = 0; p < 3; ++p) {
    int d = 16 * p + dd;                            // 0..47
    if (d <= 40) {
      f32x4 o;
#pragma unroll
      for (int j = 0; j < 4; ++j) {
        int mm = 4 * wq + j;                        // w-local
        float dot = Sw[mm * 66 + mm + d];           // col = w-local + d
        o[j] = dot / fmaxf(n1s[w0 + j] * n2s[w0 + j + d], EPS_);
      }
      *(f32x4*)(out + ((b * ND_ + d) * H_ + h) * W_ + w0) = o;
    }
  }
}

extern "C" void kernel_launch(void* const* d_in, const int* in_sizes, int n_in,
                              void* d_out, int out_size, void* d_ws, size_t ws_size,
                              hipStream_t stream) {
  const float* x1 = (const float*)d_in[0];
  const float* x2 = (const float*)d_in[1];
  float* out = (float*)d_out;
  dim3 grid(B_ * H_);
  dim3 block(1024);
  hipLaunchKernelGGL(corr_mfma, grid, block, 0, stream, x1, x2, out);
}